// Round 10
// baseline (222.713 us; speedup 1.0000x reference)
//
#include <hip/hip_runtime.h>
#include <cstdint>
#include <cstddef>

// ALiBi MHA, MI355X/gfx950. fp16 MFMA (16x16x32) pipeline.
// R14 changes vs R13:
//  - flash: q-tile 64 -> 128 rows/block (4 waves x 32 rows, 2 m-frags/wave).
//    Staging+barrier per tile unchanged but serve 2x FLOPs; K-frags shared by
//    both m MFMAs (20 ds_reads/double-tile vs 36); 32-MFMA runs. LDS 48KB
//    (Ps 16KB for 128 rows). Grid (16,32)=512 blocks=2/CU; launch_bounds
//    (256,2) caps at 256 VGPR => spill impossible (R9/R10 failure excluded).
//    Head-pairing via y-map: y<16: h=15-(y>>1); else h=(y-16)>>1; b=y&1 ->
//    co-resident partner (+256 = y+16) pairs (15,0),(14,1)..., ~70 single-
//    tile-equivalents/CU preserved.
//  - prep: grid (4096,1,4); z=3 does all four W transposes (w = x>>10) ->
//    no empty dispatches.
//  - proj/gemm_out unchanged from R13.

typedef unsigned short u16;
typedef __attribute__((ext_vector_type(8))) _Float16 half8;
typedef __attribute__((ext_vector_type(4))) float f32x4;

#define DEVI static __device__ __forceinline__
#define MFMA16(a, b, c) __builtin_amdgcn_mfma_f32_16x16x32_f16(a, b, c, 0, 0, 0)

DEVI u16 f2h_bits(float f) {
  _Float16 h = (_Float16)f;  // v_cvt_f16_f32, RNE
  union { _Float16 h; u16 u; } v; v.h = h;
  return v.u;
}

// async global->LDS, 16B per lane. LDS dest must be wave-uniform base + lane*16.
DEVI void gl_lds16(const u16* g, u16* l) {
  __builtin_amdgcn_global_load_lds(
      (const __attribute__((address_space(1))) void*)g,
      (__attribute__((address_space(3))) void*)l, 16, 0, 0);
}

#define LGKM0() __asm__ volatile("s_waitcnt lgkmcnt(0)" ::: "memory")
#define VM0()   __asm__ volatile("s_waitcnt vmcnt(0)" ::: "memory")
#define BARRIER()                       \
  do {                                  \
    __builtin_amdgcn_s_barrier();       \
    __asm__ volatile("" ::: "memory");  \
  } while (0)

// ---------------- fused prep: z 0..2 cast fp32->fp16 (q/k/v), z 3 W^T x4 ----------------
__global__ __launch_bounds__(256) void prep(
    const float* __restrict__ q, const float* __restrict__ k,
    const float* __restrict__ v, u16* __restrict__ qb, u16* __restrict__ kb,
    u16* __restrict__ vb, const float* __restrict__ W0,
    const float* __restrict__ W1, const float* __restrict__ W2,
    const float* __restrict__ W3, u16* __restrict__ T0, u16* __restrict__ T1,
    u16* __restrict__ T2, u16* __restrict__ T3, int n) {
  __shared__ float tile[32][33];
  const int z = blockIdx.z;
  if (z < 3) {
    const float* in = z == 0 ? q : (z == 1 ? k : v);
    u16* out = z == 0 ? qb : (z == 1 ? kb : vb);
    int i = (blockIdx.x * 256 + threadIdx.x) * 4;
    if (i + 3 < n) {
      const float4 vv = *(const float4*)(in + i);
      ushort4 o;
      o.x = f2h_bits(vv.x); o.y = f2h_bits(vv.y);
      o.z = f2h_bits(vv.z); o.w = f2h_bits(vv.w);
      *(ushort4*)(out + i) = o;
    }
    return;
  }
  const int w = blockIdx.x >> 10;  // 0..3
  const int idx = blockIdx.x & 1023;
  const float* W = w == 0 ? W0 : (w == 1 ? W1 : (w == 2 ? W2 : W3));
  u16* Wt = w == 0 ? T0 : (w == 1 ? T1 : (w == 2 ? T2 : T3));
  const int bx = (idx & 31) * 32;
  const int by = (idx >> 5) * 32;
  const int x = threadIdx.x & 31;
  const int y0 = threadIdx.x >> 5;  // 0..7
#pragma unroll
  for (int i = y0; i < 32; i += 8)
    tile[i][x] = W[(size_t)(by + i) * 1024 + bx + x];
  __syncthreads();
#pragma unroll
  for (int i = y0; i < 32; i += 8)
    Wt[(size_t)(bx + i) * 1024 + by + x] = f2h_bits(tile[x][i]);
}

// ---------------- GEMM body: C[4096x1024] = A[4096x1024] x Bt[1024x1024]^T ----------------
// Tile 128x128, 2x2 waves. Grid per z is (8, 32); XCD-chunked bijective swizzle
// (nwg=256 % 8 == 0): hw g2 -> L = (g2&7)*32 + (g2>>3); by'=L/8, bx'=L%8.
// 3-buffer depth-2 gl_lds pipeline: stage(kt+2) issued while computing kt;
// counted s_waitcnt vmcnt(4) (never 0 mid-loop) + raw barriers.
// 32-elem rows in LDS = 4 chunks of 8; chunk swizzle p = c ^ ((row>>1)&3).
// mode 0: fp32 out; mode 1: fp16 out row-major; mode 2: fp16 out as Vt[b][h][d][s]
DEVI void gemm_body(const u16* __restrict__ A, const u16* __restrict__ Bt,
                    void* __restrict__ Cout, int mode, u16* As, u16* Bs) {
  constexpr int K = 1024, N = 1024;
  const int t = threadIdx.x;
  const int lane = t & 63;
  const int quad = lane >> 4;
  const int l16 = lane & 15;
  const int wid = t >> 6;
  // XCD-chunked swizzle: XCD x hosts output rows by' = 4x..4x+3 (all bx)
  const int g2 = blockIdx.y * 8 + blockIdx.x;
  const int L = (g2 & 7) * 32 + (g2 >> 3);
  const int mBase = (L >> 3) * 128;
  const int nBase = (L & 7) * 128;
  const int wM = (wid >> 1) * 64;
  const int wN = (wid & 1) * 64;
  const int aswz = (quad ^ ((l16 >> 1) & 3)) << 3;  // frag-read physical col

  f32x4 acc[4][4];
#pragma unroll
  for (int i = 0; i < 4; ++i)
#pragma unroll
    for (int j = 0; j < 4; ++j) acc[i][j] = (f32x4){0.f, 0.f, 0.f, 0.f};

  // staging: 128x32 f16 tile = 8KB = 512 16B-chunks / 256 thr, A and B each
  auto stage = [&](int kt, u16* Ad, u16* Bd) {
#pragma unroll
    for (int i = 0; i < 2; ++i) {
      const int ci = i * 256 + t;
      const int row = ci >> 2;                              // 4 chunks per 32-elem row
      const int col = (((ci & 3) ^ ((ci >> 3) & 3)) << 3);  // staging-side swizzle
      gl_lds16(A + (size_t)(mBase + row) * K + kt * 32 + col, Ad + ci * 8);
      gl_lds16(Bt + (size_t)(nBase + row) * K + kt * 32 + col, Bd + ci * 8);
    }
  };

  u16 *a0 = As, *a1 = As + 4096, *a2 = As + 8192;
  u16 *b0 = Bs, *b1 = Bs + 4096, *b2 = Bs + 8192;

  // prologue: stage tiles 0,1; unconditional full drain (once per block)
  stage(0, a0, b0);
  stage(1, a1, b1);
  VM0();
  BARRIER();

  for (int kt = 0; kt < K / 32; ++kt) {
    if (kt + 2 < K / 32) stage(kt + 2, a2, b2);

    half8 a[4], b[4];
#pragma unroll
    for (int mi = 0; mi < 4; ++mi)
      a[mi] = *(const half8*)(a0 + (wM + mi * 16 + l16) * 32 + aswz);
#pragma unroll
    for (int ni = 0; ni < 4; ++ni)
      b[ni] = *(const half8*)(b0 + (wN + ni * 16 + l16) * 32 + aswz);
#pragma unroll
    for (int mi = 0; mi < 4; ++mi)
#pragma unroll
      for (int ni = 0; ni < 4; ++ni)
        acc[mi][ni] = MFMA16(a[mi], b[ni], acc[mi][ni]);

    if (kt + 1 < K / 32) {
      // outstanding gl_lds here: kt+1's 4 (+ kt+2's 4 if staged).
      if (kt + 2 < K / 32)
        __asm__ volatile("s_waitcnt vmcnt(4)" ::: "memory");  // kt+1 landed, kt+2 flying
      else
        VM0();  // tail: last tile landed
      __builtin_amdgcn_sched_barrier(0);
      LGKM0();  // own frag ds_reads done -> safe for others to overwrite old buf
      BARRIER();
    }
    u16* ta = a0; a0 = a1; a1 = a2; a2 = ta;
    u16* tb = b0; b0 = b1; b1 = b2; b2 = tb;
  }

  // epilogue. C/D layout: row = quad*4 + reg, col = lane&15 (m89/m91-verified)
#pragma unroll
  for (int mi = 0; mi < 4; ++mi) {
#pragma unroll
    for (int ni = 0; ni < 4; ++ni) {
#pragma unroll
      for (int r = 0; r < 4; ++r) {
        const int m = mBase + wM + mi * 16 + quad * 4 + r;
        const int n = nBase + wN + ni * 16 + l16;
        const float v = acc[mi][ni][r];
        if (mode == 0) {
          ((float*)Cout)[(size_t)m * N + n] = v;
        } else if (mode == 1) {
          ((u16*)Cout)[(size_t)m * N + n] = f2h_bits(v);
        } else {
          // Vt[(b*1024 + n)][s], b = m>>11, s = m&2047, S=2048
          ((u16*)Cout)[(((size_t)(m >> 11) * 1024 + n) << 11) | (size_t)(m & 2047)] = f2h_bits(v);
        }
      }
    }
  }
}

__global__ __launch_bounds__(256) void proj_qkv(
    const u16* __restrict__ qb, const u16* __restrict__ kb, const u16* __restrict__ vb,
    const u16* __restrict__ Wqt, const u16* __restrict__ Wkt, const u16* __restrict__ Wvt,
    u16* __restrict__ Qp, u16* __restrict__ Kp, u16* __restrict__ Vtp) {
  __shared__ u16 As[3 * 128 * 32];  // 24 KB (3 buffers)
  __shared__ u16 Bs[3 * 128 * 32];  // 24 KB
  const int z = blockIdx.z;
  const u16* A = z == 0 ? qb : (z == 1 ? kb : vb);
  const u16* Bt = z == 0 ? Wqt : (z == 1 ? Wkt : Wvt);
  void* C = z == 0 ? (void*)Qp : (z == 1 ? (void*)Kp : (void*)Vtp);
  gemm_body(A, Bt, C, z == 2 ? 2 : 1, As, Bs);
}

__global__ __launch_bounds__(256) void gemm_out(const u16* __restrict__ Ao,
                                                const u16* __restrict__ Wot,
                                                float* __restrict__ out) {
  __shared__ u16 As[3 * 128 * 32];
  __shared__ u16 Bs[3 * 128 * 32];
  gemm_body(Ao, Wot, out, 0, As, Bs);
}

// ---------------- flash attention + ALiBi, no-max exp2 softmax ----------------
// grid (16 qtiles of 128 rows, 32 y=(h,b)), 256 thr = 4 waves x 32 q-rows
// (2 m-frags/wave), K-tile 64, double-buffered K/V, ONE barrier per tile.
// y-map: y<16: h=15-(y>>1); else h=(y-16)>>1; b=y&1 -> co-resident CU partner
// (+256 = y+16) is the complementary head (heavy+light pairing).
// Q register-resident (staged once via Ps, 128x64). Chunk swizzle c^(row&7)
// on staging, undone at frag-read -> 2-way banks.
// ALiBi skip: tile dropped when sl2*dist > 30 (neglected mass < 2^-15 of l).
__global__ __launch_bounds__(256, 2) void flash_alibi(
    const u16* __restrict__ Qg, const u16* __restrict__ Kg,
    const u16* __restrict__ Vtg, u16* __restrict__ Og) {
  constexpr int S = 2048, Dm = 1024, HD = 64;
  __shared__ u16 Ks[2][64 * 64];   // 16 KB double-buffered
  __shared__ u16 Vs[2][64 * 64];   // 16 KB double-buffered, Vs[d][k]
  __shared__ u16 Ps[128 * 64];     // 16 KB; stages Q in prologue, then P tiles
  const int t = threadIdx.x, lane = t & 63, wid = t >> 6;  // wid 0..3
  const int quad = lane >> 4, l16 = lane & 15;
  const int qt = blockIdx.x;
  const int y = blockIdx.y;
  const int h = (y < 16) ? (15 - (y >> 1)) : ((y - 16) >> 1);
  const int b = y & 1;
  const int qBase = qt * 128;
  const size_t qRow0 = (size_t)b * S + qBase;
  const float sl2 = __builtin_amdgcn_exp2f(-0.5f * (float)(h + 1)) * 1.44269504f;
  const float sc2 = 0.125f * 1.44269504f;  // (1/sqrt(64))*log2(e)
  const int Di = (int)(30.0f / sl2);
  const int ktLo = max(0, (qBase - Di) >> 6);
  const int ktHi = min(31, (qBase + 127 + Di) >> 6);
  const int cswz = ((l16 & 7) << 3);  // frag-read chunk xor (x8 elems)
  const int pRowBase = wid * 32;      // this wave's private 32-row P region

  // prologue staging: Q tile -> Ps (128 rows x 8 chunks = 1024 chunks / 256 thr)
#pragma unroll
  for (int i = 0; i < 4; ++i) {
    const int ci = i * 256 + t;
    const int row = ci >> 3, col = (((ci & 7) ^ (row & 7)) << 3);
    gl_lds16(Qg + (qRow0 + row) * Dm + h * HD + col, Ps + ci * 8);
  }
  // prologue staging: K/V tile ktLo into buffer 0
  {
    const int kB = ktLo * 64;
#pragma unroll
    for (int i = 0; i < 2; ++i) {
      const int ci = i * 256 + t;
      const int row = ci >> 3, col = (((ci & 7) ^ (row & 7)) << 3);
      gl_lds16(Kg + ((size_t)b * S + kB + row) * Dm + h * HD + col, Ks[0] + ci * 8);
      gl_lds16(Vtg + ((size_t)(b * 16 + h) * HD + row) * S + kB + col, Vs[0] + ci * 8);
    }
  }

  // ALiBi row bias (constant over kt): bi[m][r] = sl2 * global_q_row
  float bi[2][4];
#pragma unroll
  for (int m = 0; m < 2; ++m)
#pragma unroll
    for (int r = 0; r < 4; ++r)
      bi[m][r] = sl2 * (float)(qBase + wid * 32 + m * 16 + quad * 4 + r);

  f32x4 acc_o[2][4];
#pragma unroll
  for (int m = 0; m < 2; ++m)
#pragma unroll
    for (int nd = 0; nd < 4; ++nd) acc_o[m][nd] = (f32x4){0.f, 0.f, 0.f, 0.f};
  float lrow[2][4] = {{0.f, 0.f, 0.f, 0.f}, {0.f, 0.f, 0.f, 0.f}};

  __syncthreads();  // drains vmcnt: Q + first K/V tile resident

  // Q -> registers. Wave w reads only rows [32w, 32w+32) of Ps == its own P
  // region; same-wave DS ordering makes these reads complete before later
  // P stores to the same region.
  half8 aq[2][2];  // [m][ks]
#pragma unroll
  for (int m = 0; m < 2; ++m)
#pragma unroll
    for (int ks = 0; ks < 2; ++ks) {
      const int ck = ((ks * 4 + quad) << 3) ^ cswz;
      aq[m][ks] = *(const half8*)(Ps + (pRowBase + m * 16 + l16) * HD + ck);
    }

  int bb = 0;
  for (int kt = ktLo; kt <= ktHi; ++kt) {
    const int kB = kt * 64;
    // stage NEXT tile into the other buffer, latency hidden under this tile's compute
    if (kt < ktHi) {
      const int kBn = kB + 64;
#pragma unroll
      for (int i = 0; i < 2; ++i) {
        const int ci = i * 256 + t;
        const int row = ci >> 3, col = (((ci & 7) ^ (row & 7)) << 3);
        gl_lds16(Kg + ((size_t)b * S + kBn + row) * Dm + h * HD + col, Ks[bb ^ 1] + ci * 8);
        gl_lds16(Vtg + ((size_t)(b * 16 + h) * HD + row) * S + kBn + col, Vs[bb ^ 1] + ci * 8);
      }
    }

    const u16* Kb = Ks[bb];
    const u16* Vb = Vs[bb];

    // S = Q K^T : per wave 32q x 64k (K frags shared by both m-frags)
    f32x4 s4[2][4];
#pragma unroll
    for (int m = 0; m < 2; ++m)
#pragma unroll
      for (int ni = 0; ni < 4; ++ni) s4[m][ni] = (f32x4){0.f, 0.f, 0.f, 0.f};
    __builtin_amdgcn_s_setprio(1);
#pragma unroll
    for (int ks = 0; ks < 2; ++ks) {
      const int ck = ((ks * 4 + quad) << 3) ^ cswz;
#pragma unroll
      for (int ni = 0; ni < 4; ++ni) {
        const half8 bk = *(const half8*)(Kb + (ni * 16 + l16) * HD + ck);
        s4[0][ni] = MFMA16(aq[0][ks], bk, s4[0][ni]);
        s4[1][ni] = MFMA16(aq[1][ks], bk, s4[1][ni]);
      }
    }
    __builtin_amdgcn_s_setprio(0);

    // p = exp2(s*sc2 - |bi - bj|); per-lane l partials; write swizzled P
    float bj[4];
#pragma unroll
    for (int ni = 0; ni < 4; ++ni) bj[ni] = sl2 * (float)(kB + ni * 16 + l16);
#pragma unroll
    for (int m = 0; m < 2; ++m) {
#pragma unroll
      for (int r = 0; r < 4; ++r) {
        float rs = 0.f;
        const int prow = (pRowBase + m * 16 + quad * 4 + r) * 64;
#pragma unroll
        for (int ni = 0; ni < 4; ++ni) {
          const float d = fabsf(bi[m][r] - bj[ni]);
          const float p = __builtin_amdgcn_exp2f(s4[m][ni][r] * sc2 - d);
          rs += p;
          Ps[prow + ((ni * 16 + l16) ^ (quad << 4))] = f2h_bits(p);
        }
        lrow[m][r] += rs;
      }
    }
    // P region is per-wave: wave-local LDS drain is sufficient (no block barrier)
    __asm__ volatile("s_waitcnt lgkmcnt(0)" ::: "memory");

    // O += P V : P A-frags (swizzled, 16B-contiguous), V B-frags shared
    __builtin_amdgcn_s_setprio(1);
#pragma unroll
    for (int ks = 0; ks < 2; ++ks) {
      const int pk = (ks * 32 + quad * 8) ^ ((l16 & 12) << 2);
      const int ck = ((ks * 4 + quad) << 3) ^ cswz;
      const half8 aP0 = *(const half8*)(Ps + (pRowBase + l16) * 64 + pk);
      const half8 aP1 = *(const half8*)(Ps + (pRowBase + 16 + l16) * 64 + pk);
#pragma unroll
      for (int nd = 0; nd < 4; ++nd) {
        const half8 bv = *(const half8*)(Vb + (nd * 16 + l16) * HD + ck);
        acc_o[0][nd] = MFMA16(aP0, bv, acc_o[0][nd]);
        acc_o[1][nd] = MFMA16(aP1, bv, acc_o[1][nd]);
      }
    }
    __builtin_amdgcn_s_setprio(0);

    __syncthreads();  // ONE barrier/iter: drains next-tile stage (vmcnt) + all LDS reads
    bb ^= 1;
  }

  // epilogue: reduce l across the 16 lanes sharing each row, O /= l, write f16
#pragma unroll
  for (int m = 0; m < 2; ++m) {
#pragma unroll
    for (int r = 0; r < 4; ++r) {
      float l = lrow[m][r];
      l += __shfl_xor(l, 1);
      l += __shfl_xor(l, 2);
      l += __shfl_xor(l, 4);
      l += __shfl_xor(l, 8);
      const float inv = 1.f / l;
      const int rloc = wid * 32 + m * 16 + quad * 4 + r;
#pragma unroll
      for (int nd = 0; nd < 4; ++nd)
        Og[(qRow0 + rloc) * Dm + h * HD + nd * 16 + l16] = f2h_bits(acc_o[m][nd][r] * inv);
    }
  }
}

extern "C" void kernel_launch(void* const* d_in, const int* in_sizes, int n_in,
                              void* d_out, int out_size, void* d_ws, size_t ws_size,
                              hipStream_t stream) {
  const float* q  = (const float*)d_in[0];
  const float* k  = (const float*)d_in[1];
  const float* v  = (const float*)d_in[2];
  const float* Wq = (const float*)d_in[3];
  const float* Wk = (const float*)d_in[4];
  const float* Wv = (const float*)d_in[5];
  const float* Wo = (const float*)d_in[6];
  char* ws = (char*)d_ws;
  const size_t MB = 1ull << 20;
  // workspace map (64 MB total)
  u16* qb  = (u16*)(ws + 0 * MB);    // 8 MB  q fp16
  u16* kb  = (u16*)(ws + 8 * MB);    // 8 MB
  u16* vb  = (u16*)(ws + 16 * MB);   // 8 MB
  u16* Wqt = (u16*)(ws + 24 * MB);   // 2 MB  W^T fp16
  u16* Wkt = (u16*)(ws + 26 * MB);
  u16* Wvt = (u16*)(ws + 28 * MB);
  u16* Wot = (u16*)(ws + 30 * MB);
  u16* Qp  = (u16*)(ws + 32 * MB);   // 8 MB  Q proj [4096][1024]
  u16* Kp  = (u16*)(ws + 40 * MB);   // 8 MB
  u16* Vtp = (u16*)(ws + 48 * MB);   // 8 MB  V proj transposed [b][h][64][2048]
  u16* Ao  = (u16*)(ws + 56 * MB);   // 8 MB  attention out [4096][1024]

  const int n = 2 * 2048 * 1024;
  prep<<<dim3(4096, 1, 4), 256, 0, stream>>>(q, k, v, qb, kb, vb,
                                             Wq, Wk, Wv, Wo, Wqt, Wkt, Wvt, Wot, n);
  proj_qkv<<<dim3(8, 32, 3), 256, 0, stream>>>(qb, kb, vb, Wqt, Wkt, Wvt, Qp, Kp, Vtp);
  flash_alibi<<<dim3(16, 32, 1), 256, 0, stream>>>(Qp, Kp, Vtp, Ao);
  gemm_out<<<dim3(8, 32), 256, 0, stream>>>(Ao, Wot, (float*)d_out);
}

// Round 11
// 212.627 us; speedup vs baseline: 1.0474x; 1.0474x over previous
//
#include <hip/hip_runtime.h>
#include <cstdint>
#include <cstddef>

// ALiBi MHA, MI355X/gfx950. fp16 MFMA (16x16x32) pipeline.
// R15 changes vs R13 (R14's 128-row q-tile reverted: occupancy loss ate the
// issue-amortization gain; FETCH drop confirmed but latency-bound regime):
//  - flash: SWAPPED QK^T (mfma(K,Q) -> C^T, operand reads unchanged): lane now
//    owns one q-row and 16 k-values in groups of 4 consecutive -> P written as
//    4x ds_write_b64 (packed f16, RNE) instead of 16x ds_write_b16.
//    DS ops/lane/tile 34 -> 22 (LDS pipe was the most-loaded resource).
//    Row-sum: per-lane partial + 2 quad-bit shuffles at end + wave-local LDS
//    redistribute for the epilogue. PV unchanged (row-major P, block-XOR
//    (l16&7)<<3 consistent on P write and read).
//  - prep keeps R14's compact grid (4096,1,4).
//  - GEMMs unchanged from R12/R13 (128x128, 3-buffer vmcnt(4), XCD swizzle).

typedef unsigned short u16;
typedef __attribute__((ext_vector_type(8))) _Float16 half8;
typedef __attribute__((ext_vector_type(4))) float f32x4;

#define DEVI static __device__ __forceinline__
#define MFMA16(a, b, c) __builtin_amdgcn_mfma_f32_16x16x32_f16(a, b, c, 0, 0, 0)

DEVI u16 f2h_bits(float f) {
  _Float16 h = (_Float16)f;  // v_cvt_f16_f32, RNE
  union { _Float16 h; u16 u; } v; v.h = h;
  return v.u;
}

// async global->LDS, 16B per lane. LDS dest must be wave-uniform base + lane*16.
DEVI void gl_lds16(const u16* g, u16* l) {
  __builtin_amdgcn_global_load_lds(
      (const __attribute__((address_space(1))) void*)g,
      (__attribute__((address_space(3))) void*)l, 16, 0, 0);
}

#define LGKM0() __asm__ volatile("s_waitcnt lgkmcnt(0)" ::: "memory")
#define VM0()   __asm__ volatile("s_waitcnt vmcnt(0)" ::: "memory")
#define BARRIER()                       \
  do {                                  \
    __builtin_amdgcn_s_barrier();       \
    __asm__ volatile("" ::: "memory");  \
  } while (0)

// ---------------- fused prep: z 0..2 cast fp32->fp16 (q/k/v), z 3 W^T x4 ----------------
__global__ __launch_bounds__(256) void prep(
    const float* __restrict__ q, const float* __restrict__ k,
    const float* __restrict__ v, u16* __restrict__ qb, u16* __restrict__ kb,
    u16* __restrict__ vb, const float* __restrict__ W0,
    const float* __restrict__ W1, const float* __restrict__ W2,
    const float* __restrict__ W3, u16* __restrict__ T0, u16* __restrict__ T1,
    u16* __restrict__ T2, u16* __restrict__ T3, int n) {
  __shared__ float tile[32][33];
  const int z = blockIdx.z;
  if (z < 3) {
    const float* in = z == 0 ? q : (z == 1 ? k : v);
    u16* out = z == 0 ? qb : (z == 1 ? kb : vb);
    int i = (blockIdx.x * 256 + threadIdx.x) * 4;
    if (i + 3 < n) {
      const float4 vv = *(const float4*)(in + i);
      ushort4 o;
      o.x = f2h_bits(vv.x); o.y = f2h_bits(vv.y);
      o.z = f2h_bits(vv.z); o.w = f2h_bits(vv.w);
      *(ushort4*)(out + i) = o;
    }
    return;
  }
  const int w = blockIdx.x >> 10;  // 0..3
  const int idx = blockIdx.x & 1023;
  const float* W = w == 0 ? W0 : (w == 1 ? W1 : (w == 2 ? W2 : W3));
  u16* Wt = w == 0 ? T0 : (w == 1 ? T1 : (w == 2 ? T2 : T3));
  const int bx = (idx & 31) * 32;
  const int by = (idx >> 5) * 32;
  const int x = threadIdx.x & 31;
  const int y0 = threadIdx.x >> 5;  // 0..7
#pragma unroll
  for (int i = y0; i < 32; i += 8)
    tile[i][x] = W[(size_t)(by + i) * 1024 + bx + x];
  __syncthreads();
#pragma unroll
  for (int i = y0; i < 32; i += 8)
    Wt[(size_t)(bx + i) * 1024 + by + x] = f2h_bits(tile[x][i]);
}

// ---------------- GEMM body: C[4096x1024] = A[4096x1024] x Bt[1024x1024]^T ----------------
// Tile 128x128, 2x2 waves. Grid per z is (8, 32); XCD-chunked bijective swizzle
// (nwg=256 % 8 == 0): hw g2 -> L = (g2&7)*32 + (g2>>3); by'=L/8, bx'=L%8.
// 3-buffer depth-2 gl_lds pipeline: stage(kt+2) issued while computing kt;
// counted s_waitcnt vmcnt(4) (never 0 mid-loop) + raw barriers.
// 32-elem rows in LDS = 4 chunks of 8; chunk swizzle p = c ^ ((row>>1)&3).
// mode 0: fp32 out; mode 1: fp16 out row-major; mode 2: fp16 out as Vt[b][h][d][s]
DEVI void gemm_body(const u16* __restrict__ A, const u16* __restrict__ Bt,
                    void* __restrict__ Cout, int mode, u16* As, u16* Bs) {
  constexpr int K = 1024, N = 1024;
  const int t = threadIdx.x;
  const int lane = t & 63;
  const int quad = lane >> 4;
  const int l16 = lane & 15;
  const int wid = t >> 6;
  // XCD-chunked swizzle: XCD x hosts output rows by' = 4x..4x+3 (all bx)
  const int g2 = blockIdx.y * 8 + blockIdx.x;
  const int L = (g2 & 7) * 32 + (g2 >> 3);
  const int mBase = (L >> 3) * 128;
  const int nBase = (L & 7) * 128;
  const int wM = (wid >> 1) * 64;
  const int wN = (wid & 1) * 64;
  const int aswz = (quad ^ ((l16 >> 1) & 3)) << 3;  // frag-read physical col

  f32x4 acc[4][4];
#pragma unroll
  for (int i = 0; i < 4; ++i)
#pragma unroll
    for (int j = 0; j < 4; ++j) acc[i][j] = (f32x4){0.f, 0.f, 0.f, 0.f};

  // staging: 128x32 f16 tile = 8KB = 512 16B-chunks / 256 thr, A and B each
  auto stage = [&](int kt, u16* Ad, u16* Bd) {
#pragma unroll
    for (int i = 0; i < 2; ++i) {
      const int ci = i * 256 + t;
      const int row = ci >> 2;                              // 4 chunks per 32-elem row
      const int col = (((ci & 3) ^ ((ci >> 3) & 3)) << 3);  // staging-side swizzle
      gl_lds16(A + (size_t)(mBase + row) * K + kt * 32 + col, Ad + ci * 8);
      gl_lds16(Bt + (size_t)(nBase + row) * K + kt * 32 + col, Bd + ci * 8);
    }
  };

  u16 *a0 = As, *a1 = As + 4096, *a2 = As + 8192;
  u16 *b0 = Bs, *b1 = Bs + 4096, *b2 = Bs + 8192;

  // prologue: stage tiles 0,1; unconditional full drain (once per block)
  stage(0, a0, b0);
  stage(1, a1, b1);
  VM0();
  BARRIER();

  for (int kt = 0; kt < K / 32; ++kt) {
    if (kt + 2 < K / 32) stage(kt + 2, a2, b2);

    half8 a[4], b[4];
#pragma unroll
    for (int mi = 0; mi < 4; ++mi)
      a[mi] = *(const half8*)(a0 + (wM + mi * 16 + l16) * 32 + aswz);
#pragma unroll
    for (int ni = 0; ni < 4; ++ni)
      b[ni] = *(const half8*)(b0 + (wN + ni * 16 + l16) * 32 + aswz);
#pragma unroll
    for (int mi = 0; mi < 4; ++mi)
#pragma unroll
      for (int ni = 0; ni < 4; ++ni)
        acc[mi][ni] = MFMA16(a[mi], b[ni], acc[mi][ni]);

    if (kt + 1 < K / 32) {
      // outstanding gl_lds here: kt+1's 4 (+ kt+2's 4 if staged).
      if (kt + 2 < K / 32)
        __asm__ volatile("s_waitcnt vmcnt(4)" ::: "memory");  // kt+1 landed, kt+2 flying
      else
        VM0();  // tail: last tile landed
      __builtin_amdgcn_sched_barrier(0);
      LGKM0();  // own frag ds_reads done -> safe for others to overwrite old buf
      BARRIER();
    }
    u16* ta = a0; a0 = a1; a1 = a2; a2 = ta;
    u16* tb = b0; b0 = b1; b1 = b2; b2 = tb;
  }

  // epilogue. C/D layout: row = quad*4 + reg, col = lane&15 (m89/m91-verified)
#pragma unroll
  for (int mi = 0; mi < 4; ++mi) {
#pragma unroll
    for (int ni = 0; ni < 4; ++ni) {
#pragma unroll
      for (int r = 0; r < 4; ++r) {
        const int m = mBase + wM + mi * 16 + quad * 4 + r;
        const int n = nBase + wN + ni * 16 + l16;
        const float v = acc[mi][ni][r];
        if (mode == 0) {
          ((float*)Cout)[(size_t)m * N + n] = v;
        } else if (mode == 1) {
          ((u16*)Cout)[(size_t)m * N + n] = f2h_bits(v);
        } else {
          // Vt[(b*1024 + n)][s], b = m>>11, s = m&2047, S=2048
          ((u16*)Cout)[(((size_t)(m >> 11) * 1024 + n) << 11) | (size_t)(m & 2047)] = f2h_bits(v);
        }
      }
    }
  }
}

__global__ __launch_bounds__(256) void proj_qkv(
    const u16* __restrict__ qb, const u16* __restrict__ kb, const u16* __restrict__ vb,
    const u16* __restrict__ Wqt, const u16* __restrict__ Wkt, const u16* __restrict__ Wvt,
    u16* __restrict__ Qp, u16* __restrict__ Kp, u16* __restrict__ Vtp) {
  __shared__ u16 As[3 * 128 * 32];  // 24 KB (3 buffers)
  __shared__ u16 Bs[3 * 128 * 32];  // 24 KB
  const int z = blockIdx.z;
  const u16* A = z == 0 ? qb : (z == 1 ? kb : vb);
  const u16* Bt = z == 0 ? Wqt : (z == 1 ? Wkt : Wvt);
  void* C = z == 0 ? (void*)Qp : (z == 1 ? (void*)Kp : (void*)Vtp);
  gemm_body(A, Bt, C, z == 2 ? 2 : 1, As, Bs);
}

__global__ __launch_bounds__(256) void gemm_out(const u16* __restrict__ Ao,
                                                const u16* __restrict__ Wot,
                                                float* __restrict__ out) {
  __shared__ u16 As[3 * 128 * 32];
  __shared__ u16 Bs[3 * 128 * 32];
  gemm_body(Ao, Wot, out, 0, As, Bs);
}

// ---------------- flash attention + ALiBi, no-max exp2 softmax ----------------
// grid (32 qtiles, 16 y, 2 batch), 256 thr = 4 waves x 16 q-rows, K-tile 64,
// double-buffered K/V, stage-early pipeline w/ ONE barrier per tile.
// Head map h = (y<8 ? 15-y : y-8): heavy+light pairing on co-resident CUs.
// SWAPPED QK^T: s = mfma(K-frag, Q-frag) -> lane l16 owns q-row (pRowBase+l16),
// regs = k (ni*16 + quad*4 + r). P written as packed ds_write_b64 (4 f16),
// block-XOR (l16&7)<<3 on 8-elem chunks, matching the PV A-frag read.
// Row-sum: per-lane partials, 2 quad-bit shuffles + wave-local LDS redistribute
// at the end. PV unchanged. Q register-resident (staged once via Ps).
// ALiBi skip: tile dropped when sl2*dist > 30 (neglected mass < 2^-15 of l).
__global__ __launch_bounds__(256, 4) void flash_alibi(
    const u16* __restrict__ Qg, const u16* __restrict__ Kg,
    const u16* __restrict__ Vtg, u16* __restrict__ Og) {
  constexpr int S = 2048, Dm = 1024, HD = 64;
  __shared__ u16 Ks[2][64 * 64];   // 16 KB double-buffered
  __shared__ u16 Vs[2][64 * 64];   // 16 KB double-buffered, Vs[d][k]
  __shared__ u16 Ps[64 * 64];      // 8 KB; stages Q in prologue, then P tiles
  const int t = threadIdx.x, lane = t & 63, wid = t >> 6;  // wid 0..3
  const int quad = lane >> 4, l16 = lane & 15;
  const int qt = blockIdx.x, b = blockIdx.z;
  const int y = blockIdx.y;
  const int h = (y < 8) ? (15 - y) : (y - 8);  // heavy+light pairing on CUs
  const int qBase = qt * 64;
  const size_t qRow0 = (size_t)b * S + qBase;
  const float sl2 = __builtin_amdgcn_exp2f(-0.5f * (float)(h + 1)) * 1.44269504f;
  const float sc2 = 0.125f * 1.44269504f;  // (1/sqrt(64))*log2(e)
  const int Di = (int)(30.0f / sl2);
  const int ktLo = max(0, (qBase - Di) >> 6);
  const int ktHi = min(31, (qBase + 63 + Di) >> 6);
  const int cswz = ((l16 & 7) << 3);  // chunk xor, elements (8-elem granularity)
  const int pRowBase = wid * 16;      // this wave's private 16-row P region

  // prologue staging: Q tile -> Ps (64 rows x 8 chunks = 512 chunks / 256 thr)
#pragma unroll
  for (int i = 0; i < 2; ++i) {
    const int ci = i * 256 + t;
    const int row = ci >> 3, col = (((ci & 7) ^ (row & 7)) << 3);
    gl_lds16(Qg + (qRow0 + row) * Dm + h * HD + col, Ps + ci * 8);
  }
  // prologue staging: K/V tile ktLo into buffer 0
  {
    const int kB = ktLo * 64;
#pragma unroll
    for (int i = 0; i < 2; ++i) {
      const int ci = i * 256 + t;
      const int row = ci >> 3, col = (((ci & 7) ^ (row & 7)) << 3);
      gl_lds16(Kg + ((size_t)b * S + kB + row) * Dm + h * HD + col, Ks[0] + ci * 8);
      gl_lds16(Vtg + ((size_t)(b * 16 + h) * HD + row) * S + kB + col, Vs[0] + ci * 8);
    }
  }

  // ALiBi constants (swapped layout: lane owns q = qBase + pRowBase + l16)
  const float bQ = sl2 * (float)(qBase + pRowBase + l16);
  const float sq4 = sl2 * (float)(quad * 4);
  float cK[4], slr[4];
#pragma unroll
  for (int ni = 0; ni < 4; ++ni) cK[ni] = sl2 * (float)(ni * 16);
#pragma unroll
  for (int r = 0; r < 4; ++r) slr[r] = sl2 * (float)r;

  f32x4 acc_o[4];
#pragma unroll
  for (int nd = 0; nd < 4; ++nd) acc_o[nd] = (f32x4){0.f, 0.f, 0.f, 0.f};
  float lsum = 0.f;

  __syncthreads();  // drains vmcnt: Q + first K/V tile resident

  // Q -> registers. Wave w reads only rows [16w, 16w+16) of Ps == its own P
  // region; same-wave DS ordering completes these before later P stores.
  half8 aq[2];
#pragma unroll
  for (int ks = 0; ks < 2; ++ks) {
    const int ck = ((ks * 4 + quad) << 3) ^ cswz;
    aq[ks] = *(const half8*)(Ps + (pRowBase + l16) * HD + ck);
  }

  int bb = 0;
  for (int kt = ktLo; kt <= ktHi; ++kt) {
    const int kB = kt * 64;
    // stage NEXT tile into the other buffer, latency hidden under this tile's compute
    if (kt < ktHi) {
      const int kBn = kB + 64;
#pragma unroll
      for (int i = 0; i < 2; ++i) {
        const int ci = i * 256 + t;
        const int row = ci >> 3, col = (((ci & 7) ^ (row & 7)) << 3);
        gl_lds16(Kg + ((size_t)b * S + kBn + row) * Dm + h * HD + col, Ks[bb ^ 1] + ci * 8);
        gl_lds16(Vtg + ((size_t)(b * 16 + h) * HD + row) * S + kBn + col, Vs[bb ^ 1] + ci * 8);
      }
    }

    const u16* Kb = Ks[bb];
    const u16* Vb = Vs[bb];

    // S^T = K Q^T (swapped): per wave 64k x 16q; operand reads identical to
    // the unswapped version, output C[k_local=quad*4+r][q=l16].
    f32x4 s4[4];
#pragma unroll
    for (int ni = 0; ni < 4; ++ni) s4[ni] = (f32x4){0.f, 0.f, 0.f, 0.f};
    __builtin_amdgcn_s_setprio(1);
#pragma unroll
    for (int ks = 0; ks < 2; ++ks) {
      const int ck = ((ks * 4 + quad) << 3) ^ cswz;
#pragma unroll
      for (int ni = 0; ni < 4; ++ni) {
        const half8 bk = *(const half8*)(Kb + (ni * 16 + l16) * HD + ck);
        s4[ni] = MFMA16(bk, aq[ks], s4[ni]);  // SWAPPED operands
      }
    }
    __builtin_amdgcn_s_setprio(0);

    // p = exp2(s*sc2 - sl2*|i-j|), i = lane's q, j = kB + ni*16 + quad*4 + r.
    // 4 consecutive k per (ni): pack 4 f16 -> one ds_write_b64.
    const float tb = bQ - sl2 * (float)kB - sq4;  // sl2*(i - kB - quad*4)
    float rs = 0.f;
#pragma unroll
    for (int ni = 0; ni < 4; ++ni) {
      const float tni = tb - cK[ni];
      float pv0 = __builtin_amdgcn_exp2f(s4[ni][0] * sc2 - fabsf(tni));
      float pv1 = __builtin_amdgcn_exp2f(s4[ni][1] * sc2 - fabsf(tni - slr[1]));
      float pv2 = __builtin_amdgcn_exp2f(s4[ni][2] * sc2 - fabsf(tni - slr[2]));
      float pv3 = __builtin_amdgcn_exp2f(s4[ni][3] * sc2 - fabsf(tni - slr[3]));
      rs += (pv0 + pv1) + (pv2 + pv3);
      uint2 wv;
      wv.x = (uint32_t)f2h_bits(pv0) | ((uint32_t)f2h_bits(pv1) << 16);
      wv.y = (uint32_t)f2h_bits(pv2) | ((uint32_t)f2h_bits(pv3) << 16);
      *(uint2*)(Ps + (pRowBase + l16) * 64 + ((ni * 16 + quad * 4) ^ cswz)) = wv;
    }
    lsum += rs;
    // P region is per-wave: wave-local LDS drain is sufficient (no block barrier)
    LGKM0();

    // O += P V : P A-frags (row-major, block-XOR'd chunks), V B-frags
    __builtin_amdgcn_s_setprio(1);
#pragma unroll
    for (int ks = 0; ks < 2; ++ks) {
      const int pk = (ks * 32 + quad * 8) ^ cswz;
      const int ck = ((ks * 4 + quad) << 3) ^ cswz;
      const half8 aP = *(const half8*)(Ps + (pRowBase + l16) * 64 + pk);
#pragma unroll
      for (int nd = 0; nd < 4; ++nd) {
        const half8 bv = *(const half8*)(Vb + (nd * 16 + l16) * HD + ck);
        acc_o[nd] = MFMA16(aP, bv, acc_o[nd]);
      }
    }
    __builtin_amdgcn_s_setprio(0);

    __syncthreads();  // ONE barrier/iter: drains next-tile stage (vmcnt) + all LDS reads
    bb ^= 1;
  }

  // epilogue: l(q=l16) = sum over quads (2 shuffles); redistribute via the
  // wave's private Ps region (reused as float scratch); O /= l, write f16.
  float l = lsum;
  l += __shfl_xor(l, 16);
  l += __shfl_xor(l, 32);
  float* lsh = (float*)Ps + wid * 512;  // wave-private 2KB region of Ps
  if (quad == 0) lsh[l16] = l;
  LGKM0();
#pragma unroll
  for (int r = 0; r < 4; ++r) {
    const float inv = 1.f / lsh[quad * 4 + r];
    const int rloc = wid * 16 + quad * 4 + r;
#pragma unroll
    for (int nd = 0; nd < 4; ++nd)
      Og[(qRow0 + rloc) * Dm + h * HD + nd * 16 + l16] = f2h_bits(acc_o[nd][r] * inv);
  }
}

extern "C" void kernel_launch(void* const* d_in, const int* in_sizes, int n_in,
                              void* d_out, int out_size, void* d_ws, size_t ws_size,
                              hipStream_t stream) {
  const float* q  = (const float*)d_in[0];
  const float* k  = (const float*)d_in[1];
  const float* v  = (const float*)d_in[2];
  const float* Wq = (const float*)d_in[3];
  const float* Wk = (const float*)d_in[4];
  const float* Wv = (const float*)d_in[5];
  const float* Wo = (const float*)d_in[6];
  char* ws = (char*)d_ws;
  const size_t MB = 1ull << 20;
  // workspace map (64 MB total)
  u16* qb  = (u16*)(ws + 0 * MB);    // 8 MB  q fp16
  u16* kb  = (u16*)(ws + 8 * MB);    // 8 MB
  u16* vb  = (u16*)(ws + 16 * MB);   // 8 MB
  u16* Wqt = (u16*)(ws + 24 * MB);   // 2 MB  W^T fp16
  u16* Wkt = (u16*)(ws + 26 * MB);
  u16* Wvt = (u16*)(ws + 28 * MB);
  u16* Wot = (u16*)(ws + 30 * MB);
  u16* Qp  = (u16*)(ws + 32 * MB);   // 8 MB  Q proj [4096][1024]
  u16* Kp  = (u16*)(ws + 40 * MB);   // 8 MB
  u16* Vtp = (u16*)(ws + 48 * MB);   // 8 MB  V proj transposed [b][h][64][2048]
  u16* Ao  = (u16*)(ws + 56 * MB);   // 8 MB  attention out [4096][1024]

  const int n = 2 * 2048 * 1024;
  prep<<<dim3(4096, 1, 4), 256, 0, stream>>>(q, k, v, qb, kb, vb,
                                             Wq, Wk, Wv, Wo, Wqt, Wkt, Wvt, Wot, n);
  proj_qkv<<<dim3(8, 32, 3), 256, 0, stream>>>(qb, kb, vb, Wqt, Wkt, Wvt, Qp, Kp, Vtp);
  flash_alibi<<<dim3(32, 16, 2), 256, 0, stream>>>(Qp, Kp, Vtp, Ao);
  gemm_out<<<dim3(8, 32), 256, 0, stream>>>(Ao, Wot, (float*)d_out);
}